// Round 2
// baseline (842.639 us; speedup 1.0000x reference)
//
#include <hip/hip_runtime.h>
#include <hip/hip_bf16.h>
#include <math.h>

// LurieNet: X_{t+1} = X_t + h*(A X_t + B tanh(C X_t + by) + bx), 511 steps,
// state (128 x 512 batch), output (512, 512, 128) fp32.
// Reformulated with Y := C X + by as state:  S = [X; Y] (256 x 512),
//   V = [X_bf16; tanh(Y)],  S += h*(M V) + h*b2,  M = [[A,B],[CA,CB]].
// R2 structure: TWO launches (launch-gap cost ~40us each was #2 bottleneck):
//   k_expm (5 blocks; last-finishing block runs prep_body = A,B,C,CA,CB,Y0,
//           cbx, fragment packing via device-scope atomic handshake)
//   k_main (511-step loop; t=0 output store folded into its prologue).

typedef __attribute__((ext_vector_type(8))) short short8;
typedef __attribute__((ext_vector_type(4))) float f32x4;

// workspace layout (float units)
#define OFF_UO   0            // 5 * 16384 : UA_o, UB_o, VB_o, UC_o, VC_o
#define OFF_A    81920
#define OFF_B    98304
#define OFF_C    114688
#define OFF_CA   131072
#define OFF_CB   147456
#define OFF_Y0   163840       // 128 x 512
#define OFF_CBX  229376       // 128
#define OFF_HBP  229504       // 16*64*4
#define OFF_S0P  233600       // 256*512
#define OFF_MF   364672       // ushort area: 131072 bf16

__device__ __forceinline__ unsigned short f2bf(float x){
  unsigned int u = __float_as_uint(x);
  unsigned int r = u + 0x7FFFu + ((u >> 16) & 1u);   // RNE
  return (unsigned short)(r >> 16);
}
__device__ __forceinline__ float bf2f(unsigned short b){
  return __uint_as_float(((unsigned int)b) << 16);
}
__device__ __forceinline__ void split_bf(float x, unsigned short& h, unsigned short& l){
  h = f2bf(x);
  l = f2bf(x - bf2f(h));
}
// v_cvt_pk_bf16_f32 path (RNE, matches f2bf): low16 = bf(a), high16 = bf(b)
__device__ __forceinline__ unsigned int pk2(float a, float b){
  union { __hip_bfloat162 h; unsigned int u; } cv;
  cv.h = __float22bfloat162_rn(make_float2(a, b));
  return cv.u;
}
__device__ __forceinline__ void split2(float x0, float x1,
                                       unsigned int& hu, unsigned int& lu){
  hu = pk2(x0, x1);
  float r0 = x0 - __uint_as_float((hu & 0xFFFFu) << 16);
  float r1 = x1 - __uint_as_float(hu & 0xFFFF0000u);
  lu = pk2(r0, r1);
}
__device__ __forceinline__ f32x4 mfma16(short8 a, short8 b, f32x4 c){
  return __builtin_amdgcn_mfma_f32_16x16x32_bf16(a, b, c, 0, 0, 0);
}
// Branchless tanh: 1 - 2/(exp(2y)+1). v_exp + v_rcp, no divergence.
__device__ __forceinline__ float tanh_fast(float y){
  float e = __expf(2.f * y);
  return 1.f - 2.f * __builtin_amdgcn_rcpf(e + 1.f);
}

// ---------------- prep: A,B,C (3x 128^3 hi/lo matmul), CA,CB, Y0, cbx, pack.
// Runs as the tail of k_expm in the LAST-finishing block (single block, 1024 thr).
__device__ void prep_body(float* __restrict__ ws,
    const float* __restrict__ SBm, const float* __restrict__ SCm,
    const float* __restrict__ GA1, const float* __restrict__ GAk,
    const float* __restrict__ GAp, const float* __restrict__ YA,
    const float* __restrict__ X0, const float* __restrict__ bx,
    const float* __restrict__ by)
{
  __shared__ float dvec[128];
  __shared__ float scal[4];
  __shared__ float sb[128], sc[128];
  const int tid = threadIdx.x;
  const int lane = tid & 63, w = tid >> 6, q = lane >> 4, m16 = lane & 15;
  const int rt = w >> 2, cp = w & 3;

  // stage diagonals once; LDS-only top-2 scan
  if (tid < 128){ sb[tid] = fabsf(SBm[tid*129]); sc[tid] = fabsf(SCm[tid*129]); }
  __syncthreads();
  if (tid == 0){
    float b1=0.f,b2=0.f,c1=0.f,c2=0.f;
    for (int i=0;i<128;++i){
      float vb = sb[i];
      if (vb > b1){ b2=b1; b1=vb; } else if (vb > b2) b2=vb;
      float vc = sc[i];
      if (vc > c1){ c2=c1; c1=vc; } else if (vc > c2) c2=vc;
    }
    float alpha = sqrtf(8.f*(b1*b1*c1*c1 + b2*b2*c2*c2));  // 4*K*G^2 = 8
    float sa0 = GA1[0];
    float sa2 = -(alpha + sa0) - (fabsf(GAk[0]) + 1e-5f);
    float mm  = fminf(fminf(sa0, sa2), 0.f);
    scal[0]=sa0; scal[1]=sa2; scal[2]=mm;
  }
  __syncthreads();

  // ---- A, B, C
  for (int mat = 0; mat < 3; ++mat){
    if (mat == 0){
      if (tid < 128){
        float v;
        if (tid == 0) v = scal[0];
        else if (tid == 1) v = scal[1];
        else v = scal[2] - fabsf(GAp[(tid-2)*127]);
        dvec[tid] = v;
      }
    } else if (mat == 1){
      if (tid < 128) dvec[tid] = sb[tid];
    } else {
      if (tid < 128) dvec[tid] = sc[tid];
    }
    __syncthreads();

    const float* U; const float* V; float* Out;
    if (mat == 0){ U = ws + OFF_UO;          V = U;                    Out = ws + OFF_A; }
    else if (mat == 1){ U = ws + OFF_UO + 16384; V = ws + OFF_UO + 32768; Out = ws + OFF_B; }
    else { U = ws + OFF_UO + 49152; V = ws + OFF_UO + 65536; Out = ws + OFF_C; }

    short8 Ah[2][4], Al[2][4];
    #pragma unroll
    for (int rr=0; rr<2; ++rr){
      const int row = rt*32 + rr*16 + m16;
      #pragma unroll
      for (int c=0; c<4; ++c){
        const float* up = U + row*128 + c*32 + q*8;
        const f32x4 u0 = *(const f32x4*)up;
        const f32x4 u1 = *(const f32x4*)(up + 4);
        short8 hh, ll;
        #pragma unroll
        for (int jj=0; jj<4; ++jj){
          unsigned short hb_, lb_;
          split_bf(u0[jj], hb_, lb_); hh[jj]   = (short)hb_; ll[jj]   = (short)lb_;
          split_bf(u1[jj], hb_, lb_); hh[jj+4] = (short)hb_; ll[jj+4] = (short)lb_;
        }
        Ah[rr][c] = hh; Al[rr][c] = ll;
      }
    }
    f32x4 acc[2][2];
    #pragma unroll
    for (int rr=0; rr<2; ++rr)
      #pragma unroll
      for (int cc=0; cc<2; ++cc) acc[rr][cc] = (f32x4){0.f,0.f,0.f,0.f};

    #pragma unroll
    for (int cc=0; cc<2; ++cc){
      const int n = cp*32 + cc*16 + m16;
      #pragma unroll
      for (int c=0; c<4; ++c){
        const int k0 = c*32 + q*8;
        const float* vp = V + n*128 + k0;            // B[k][n] = dvec[k]*V[n][k]
        const f32x4 v0 = *(const f32x4*)vp;
        const f32x4 v1 = *(const f32x4*)(vp + 4);
        short8 bh, bl;
        #pragma unroll
        for (int jj=0; jj<4; ++jj){
          unsigned short hb_, lb_;
          split_bf(v0[jj]*dvec[k0+jj],   hb_, lb_); bh[jj]   = (short)hb_; bl[jj]   = (short)lb_;
          split_bf(v1[jj]*dvec[k0+4+jj], hb_, lb_); bh[jj+4] = (short)hb_; bl[jj+4] = (short)lb_;
        }
        #pragma unroll
        for (int rr=0; rr<2; ++rr){
          acc[rr][cc] = mfma16(Ah[rr][c], bh, acc[rr][cc]);
          acc[rr][cc] = mfma16(Al[rr][c], bh, acc[rr][cc]);
          acc[rr][cc] = mfma16(Ah[rr][c], bl, acc[rr][cc]);
        }
      }
    }
    #pragma unroll
    for (int rr=0; rr<2; ++rr){
      #pragma unroll
      for (int cc=0; cc<2; ++cc){
        const int cg  = cp*32 + cc*16 + m16;
        const int rg0 = rt*32 + rr*16 + q*4;
        #pragma unroll
        for (int i=0; i<4; ++i){
          float x = acc[rr][cc][i];
          if (mat == 0){
            const int r = rg0 + i;
            float sk = 0.f;
            if (r < cg) sk = YA[r*128 + cg];
            else if (r > cg) sk = -YA[cg*128 + r];
            x = 0.5f*x + 0.5f*sk;
          }
          Out[(rg0+i)*128 + cg] = x;
        }
      }
    }
    __syncthreads();
  }

  // ---- C row-fragments (shared by CA, CB, Y0)
  const float* Cm = ws + OFF_C;
  short8 Ch[2][4], Cl[2][4];
  #pragma unroll
  for (int rr=0; rr<2; ++rr){
    const int row = rt*32 + rr*16 + m16;
    #pragma unroll
    for (int c=0; c<4; ++c){
      const float* up = Cm + row*128 + c*32 + q*8;
      const f32x4 u0 = *(const f32x4*)up;
      const f32x4 u1 = *(const f32x4*)(up + 4);
      short8 hh, ll;
      #pragma unroll
      for (int jj=0; jj<4; ++jj){
        unsigned short hb_, lb_;
        split_bf(u0[jj], hb_, lb_); hh[jj]   = (short)hb_; ll[jj]   = (short)lb_;
        split_bf(u1[jj], hb_, lb_); hh[jj+4] = (short)hb_; ll[jj+4] = (short)lb_;
      }
      Ch[rr][c] = hh; Cl[rr][c] = ll;
    }
  }

  // ---- CA, CB
  for (int role = 0; role < 2; ++role){
    const float* Rm = ws + ((role == 0) ? OFF_A : OFF_B);
    f32x4 acc[2][2];
    #pragma unroll
    for (int rr=0; rr<2; ++rr)
      #pragma unroll
      for (int cc=0; cc<2; ++cc) acc[rr][cc] = (f32x4){0.f,0.f,0.f,0.f};
    #pragma unroll
    for (int cc=0; cc<2; ++cc){
      const int n = cp*32 + cc*16 + m16;
      #pragma unroll
      for (int c=0; c<4; ++c){
        const int k0 = c*32 + q*8;
        short8 bh, bl;
        #pragma unroll
        for (int jj=0; jj<8; ++jj){
          unsigned short hb_, lb_;
          split_bf(Rm[(k0+jj)*128 + n], hb_, lb_);
          bh[jj] = (short)hb_; bl[jj] = (short)lb_;
        }
        #pragma unroll
        for (int rr=0; rr<2; ++rr){
          acc[rr][cc] = mfma16(Ch[rr][c], bh, acc[rr][cc]);
          acc[rr][cc] = mfma16(Cl[rr][c], bh, acc[rr][cc]);
          acc[rr][cc] = mfma16(Ch[rr][c], bl, acc[rr][cc]);
        }
      }
    }
    float* Om = ws + ((role == 0) ? OFF_CA : OFF_CB);
    #pragma unroll
    for (int rr=0; rr<2; ++rr){
      #pragma unroll
      for (int cc=0; cc<2; ++cc){
        const int cg  = cp*32 + cc*16 + m16;
        const int rg0 = rt*32 + rr*16 + q*4;
        #pragma unroll
        for (int i=0; i<4; ++i) Om[(rg0+i)*128 + cg] = acc[rr][cc][i];
      }
    }
  }

  // ---- Y0 = C X0^T + by  (4 panels of 128 batch cols)
  for (int pan = 0; pan < 4; ++pan){
    const int bcolbase = pan * 128;
    f32x4 acc[2][2];
    #pragma unroll
    for (int rr=0; rr<2; ++rr)
      #pragma unroll
      for (int cc=0; cc<2; ++cc) acc[rr][cc] = (f32x4){0.f,0.f,0.f,0.f};
    #pragma unroll
    for (int cc=0; cc<2; ++cc){
      const int bcol = bcolbase + cp*32 + cc*16 + m16;
      #pragma unroll
      for (int c=0; c<4; ++c){
        const int k0 = c*32 + q*8;
        const float* xp = X0 + bcol*128 + k0;      // B[k][b] = X0[b][k]
        const f32x4 x0v = *(const f32x4*)xp;
        const f32x4 x1v = *(const f32x4*)(xp + 4);
        short8 bh, bl;
        #pragma unroll
        for (int jj=0; jj<4; ++jj){
          unsigned short hb_, lb_;
          split_bf(x0v[jj], hb_, lb_); bh[jj]   = (short)hb_; bl[jj]   = (short)lb_;
          split_bf(x1v[jj], hb_, lb_); bh[jj+4] = (short)hb_; bl[jj+4] = (short)lb_;
        }
        #pragma unroll
        for (int rr=0; rr<2; ++rr){
          acc[rr][cc] = mfma16(Ch[rr][c], bh, acc[rr][cc]);
          acc[rr][cc] = mfma16(Cl[rr][c], bh, acc[rr][cc]);
          acc[rr][cc] = mfma16(Ch[rr][c], bl, acc[rr][cc]);
        }
      }
    }
    float* Y0p = ws + OFF_Y0;
    #pragma unroll
    for (int rr=0; rr<2; ++rr){
      #pragma unroll
      for (int cc=0; cc<2; ++cc){
        const int bcol = bcolbase + cp*32 + cc*16 + m16;
        const int rg0  = rt*32 + rr*16 + q*4;
        #pragma unroll
        for (int i=0; i<4; ++i)
          Y0p[(rg0+i)*512 + bcol] = acc[rr][cc][i] + by[rg0+i];
      }
    }
  }

  // ---- cbx = C @ bx (8 partial lanes per row, shfl reduce within 8-group)
  {
    const int r = tid >> 3, pp = tid & 7;
    float s = 0.f;
    const float* cr = Cm + r*128 + pp*16;
    #pragma unroll
    for (int j2=0; j2<16; ++j2) s += cr[j2]*bx[pp*16+j2];
    s += __shfl_xor(s, 1); s += __shfl_xor(s, 2); s += __shfl_xor(s, 4);
    if (pp == 0) ws[OFF_CBX + r] = s;
  }
  __syncthreads();   // CA/CB/Y0/cbx all visible for packing

  // ---- pack: M fragments (bf16 hi/lo), S0, h*b2
  unsigned short* Mf = (unsigned short*)(ws + OFF_MF);
  for (int fid = tid; fid < 41984; fid += 1024){
    if (fid < 8192){               // M frags
      const int pw = fid >> 9, pc = (fid >> 6) & 7, pl = fid & 63;
      const int pq = pl >> 4, pm = pl & 15;
      const int row = pw*16 + pm;            // 0..255 of M = [[A,B],[CA,CB]]
      const int k0 = pc*32 + pq*8;           // 0..255
      const float* src;
      if (row < 128) src = (k0 < 128) ? (ws + OFF_A  + row*128 + k0)
                                      : (ws + OFF_B  + row*128 + (k0-128));
      else           src = (k0 < 128) ? (ws + OFF_CA + (row-128)*128 + k0)
                                      : (ws + OFF_CB + (row-128)*128 + (k0-128));
      unsigned short* dh = Mf + (size_t)pw*8192 + pc*1024 + pl*8;
      unsigned short* dl = dh + 512;
      #pragma unroll
      for (int j=0; j<8; ++j){
        unsigned short hb_, lb_;
        split_bf(src[j], hb_, lb_);
        dh[j] = hb_; dl[j] = lb_;
      }
    } else if (fid < 40960){       // S0 packed per (wg, tile, lane)
      const int t = fid - 8192;
      const int pwg = t >> 10, pw = (t >> 6) & 15, pl = t & 63;
      const int pq = pl >> 4, pm = pl & 15;
      const int col = pwg*16 + pm;
      const int r0 = pw*16 + pq*4;
      f32x4 v;
      if (r0 < 128){
        v = *(const f32x4*)(X0 + col*128 + r0);
      } else {
        const float* Y0p = ws + OFF_Y0;
        v[0] = Y0p[(r0-128)*512 + col]; v[1] = Y0p[(r0-127)*512 + col];
        v[2] = Y0p[(r0-126)*512 + col]; v[3] = Y0p[(r0-125)*512 + col];
      }
      *(f32x4*)(ws + OFF_S0P + (size_t)t*4) = v;
    } else {                       // h*b2 packed per (tile, lane)
      const int t2 = fid - 40960;
      const int pw = t2 >> 6, pl = t2 & 63, pq = pl >> 4;
      const int r0 = pw*16 + pq*4;
      f32x4 v;
      #pragma unroll
      for (int i=0; i<4; ++i){
        const int r = r0 + i;
        v[i] = 0.01f * ((r < 128) ? bx[r] : ws[OFF_CBX + (r-128)]);
      }
      *(f32x4*)(ws + OFF_HBP + (size_t)t2*4) = v;
    }
  }
}

// ---------------- K1: 5 x expm(skew(Z)) via Taylor-12 Horner, hi/lo bf16 MFMA.
// Tail: device-scope handshake; last-finishing block runs prep_body.
__global__ __launch_bounds__(1024) void k_expm(
    const float* __restrict__ UA, const float* __restrict__ UB,
    const float* __restrict__ VB, const float* __restrict__ UC,
    const float* __restrict__ VC, float* __restrict__ ws,
    const float* __restrict__ SBm, const float* __restrict__ SCm,
    const float* __restrict__ GA1, const float* __restrict__ GAk,
    const float* __restrict__ GAp, const float* __restrict__ YA,
    const float* __restrict__ X0, const float* __restrict__ bx,
    const float* __restrict__ by, unsigned int* __restrict__ flag)
{
  const int b = blockIdx.x;
  const float* Z = (b==0)?UA:((b==1)?UB:((b==2)?VB:((b==3)?UC:VC)));
  float* Eo = ws + OFF_UO + b*16384;

  __shared__ unsigned short Hh[2][128][136];  // H^T (n-major), bf16 hi
  __shared__ unsigned short Hl[2][128][136];  // bf16 lo

  const int tid = threadIdx.x, lane = tid & 63, w = tid >> 6;
  const int q = lane >> 4, m16 = lane & 15;
  const int rt = w >> 2, cp = w & 3;

  short8 Rh[2][4], Rl[2][4];
  #pragma unroll
  for (int rr=0; rr<2; ++rr){
    const int row = rt*32 + rr*16 + m16;
    #pragma unroll
    for (int c=0; c<4; ++c){
      short8 hh, ll;
      #pragma unroll
      for (int j=0; j<8; ++j){
        const int k = c*32 + q*8 + j;
        float z = 0.f;
        if (row < k)      z =  Z[row*128 + k];
        else if (row > k) z = -Z[k*128 + row];
        unsigned short hb_, lb_;
        split_bf(z, hb_, lb_);
        hh[j] = (short)hb_; ll[j] = (short)lb_;
      }
      Rh[rr][c] = hh; Rl[rr][c] = ll;
    }
  }
  { // H = I into buffer 0
    unsigned short* hp = &Hh[0][0][0];
    unsigned short* lp = &Hl[0][0][0];
    for (int idx = tid; idx < 128*136; idx += 1024){
      const int n = idx / 136, k = idx - n*136;
      hp[idx] = (n == k) ? (unsigned short)0x3F80u : (unsigned short)0u;
      lp[idx] = 0u;
    }
  }
  __syncthreads();

  int cur = 0;
  for (int j = 12; j >= 1; --j){          // H = I + (R*H)/j
    const float rj = 1.f / (float)j;
    f32x4 acc[2][2];
    #pragma unroll
    for (int rr=0; rr<2; ++rr)
      #pragma unroll
      for (int cc=0; cc<2; ++cc) acc[rr][cc] = (f32x4){0.f,0.f,0.f,0.f};

    #pragma unroll
    for (int cc=0; cc<2; ++cc){
      const int n = cp*32 + cc*16 + m16;
      #pragma unroll
      for (int c=0; c<4; ++c){
        const short8 bh = *(const short8*)&Hh[cur][n][c*32 + q*8];
        const short8 bl = *(const short8*)&Hl[cur][n][c*32 + q*8];
        #pragma unroll
        for (int rr=0; rr<2; ++rr){
          acc[rr][cc] = mfma16(Rh[rr][c], bh, acc[rr][cc]);
          acc[rr][cc] = mfma16(Rl[rr][c], bh, acc[rr][cc]);
          acc[rr][cc] = mfma16(Rh[rr][c], bl, acc[rr][cc]);
        }
      }
    }
    if (j > 1){
      const int nxt = cur ^ 1;
      #pragma unroll
      for (int rr=0; rr<2; ++rr){
        #pragma unroll
        for (int cc=0; cc<2; ++cc){
          const int cg  = cp*32 + cc*16 + m16;
          const int rg0 = rt*32 + rr*16 + q*4;
          float x0 = acc[rr][cc][0]*rj + ((rg0+0)==cg ? 1.f : 0.f);
          float x1 = acc[rr][cc][1]*rj + ((rg0+1)==cg ? 1.f : 0.f);
          float x2 = acc[rr][cc][2]*rj + ((rg0+2)==cg ? 1.f : 0.f);
          float x3 = acc[rr][cc][3]*rj + ((rg0+3)==cg ? 1.f : 0.f);
          unsigned int h0,l0,h1,l1;
          split2(x0, x1, h0, l0);
          split2(x2, x3, h1, l1);
          *(uint2*)&Hh[nxt][cg][rg0] = make_uint2(h0, h1);
          *(uint2*)&Hl[nxt][cg][rg0] = make_uint2(l0, l1);
        }
      }
      __syncthreads();
      cur = nxt;
    } else {
      #pragma unroll
      for (int rr=0; rr<2; ++rr){
        #pragma unroll
        for (int cc=0; cc<2; ++cc){
          const int cg  = cp*32 + cc*16 + m16;
          const int rg0 = rt*32 + rr*16 + q*4;
          #pragma unroll
          for (int i=0; i<4; ++i)
            Eo[(rg0+i)*128 + cg] = acc[rr][cc][i] + ((rg0+i)==cg ? 1.f : 0.f);
        }
      }
    }
  }

  // ---- handshake: last block to arrive runs prep_body
  __threadfence();               // release own Eo stores (device scope)
  __syncthreads();
  __shared__ unsigned int rank_s;
  if (tid == 0) rank_s = atomicAdd(flag, 1u);
  __syncthreads();
  if (rank_s == 4u){
    __threadfence();             // acquire other blocks' Eo stores
    prep_body(ws, SBm, SCm, GA1, GAk, GAp, YA, X0, bx, by);
  }
}

// ---------------- K5: 511-step recurrence. 32 WGs x 512 thr.
// Each wave owns 16 X rows (tile w) AND 16 Y rows (tile 8+w): symmetric waves.
// Y MFMAs first, X MFMAs second (Y finish overlaps X MFMA pipe). Raw barrier
// with lgkmcnt-only drain; global stores ride across steps. t=0 out in prologue.
__global__ __launch_bounds__(512) void k_main(const float* __restrict__ ws,
                                              float* __restrict__ out)
{
  const unsigned short* Mf = (const unsigned short*)(ws + OFF_MF);
  const float* S0p = ws + OFF_S0P;
  const float* hbp = ws + OFF_HBP;

  __shared__ unsigned short Vb[2][16][264];  // V^T: [buf][col n][state row k], bf16

  const int tid = threadIdx.x, lane = tid & 63, w = tid >> 6, wg = blockIdx.x;
  const int q = lane >> 4, m16 = lane & 15;

  short8 Mh[2][8], Ml[2][8];
  #pragma unroll
  for (int r2=0; r2<2; ++r2){
    const unsigned short* bp = Mf + (size_t)(w + 8*r2)*8192 + lane*8;
    #pragma unroll
    for (int c=0; c<8; ++c){
      Mh[r2][c] = *(const short8*)(bp + c*1024);
      Ml[r2][c] = *(const short8*)(bp + c*1024 + 512);
    }
  }
  f32x4 S[2], hb[2];
  #pragma unroll
  for (int r2=0; r2<2; ++r2){
    S[r2]  = *(const f32x4*)(S0p + (size_t)((wg*16 + w + 8*r2)*64 + lane)*4);
    hb[r2] = *(const f32x4*)(hbp + (size_t)((w + 8*r2)*64 + lane)*4);
  }
  const int r0x = w*16 + q*4;           // owned X rows (V position = row)
  const int r0y = 128 + w*16 + q*4;     // owned Y rows (V position = 128+row)

  float* op = out + (size_t)(wg*16 + m16)*65536 + r0x;   // + t*128
  *(f32x4*)op = S[0];                   // t = 0 output (S0P X-part == X0 exactly)

  { // initial V = [X0_bf16 ; tanh(Y0)]
    *(uint2*)&Vb[0][m16][r0x] = make_uint2(pk2(S[0][0], S[0][1]), pk2(S[0][2], S[0][3]));
    float t0 = tanh_fast(S[1][0]), t1 = tanh_fast(S[1][1]);
    float t2 = tanh_fast(S[1][2]), t3 = tanh_fast(S[1][3]);
    *(uint2*)&Vb[0][m16][r0y] = make_uint2(pk2(t0, t1), pk2(t2, t3));
  }
  asm volatile("s_waitcnt lgkmcnt(0)" ::: "memory");
  __builtin_amdgcn_s_barrier();
  asm volatile("" ::: "memory");

  int cur = 0;
  for (int t = 1; t < 512; ++t){
    const unsigned short* vrow = &Vb[cur][m16][q*8];
    short8 vf[8];
    #pragma unroll
    for (int c=0; c<8; ++c) vf[c] = *(const short8*)(vrow + c*32);

    // Y tile first...
    f32x4 aH1 = (f32x4){0.f,0.f,0.f,0.f}, aL1 = (f32x4){0.f,0.f,0.f,0.f};
    #pragma unroll
    for (int c=0; c<8; ++c){
      aH1 = mfma16(Mh[1][c], vf[c], aH1);
      aL1 = mfma16(Ml[1][c], vf[c], aL1);
    }
    // ...X tile second; Y finish is independent of these MFMAs.
    f32x4 aH0 = (f32x4){0.f,0.f,0.f,0.f}, aL0 = (f32x4){0.f,0.f,0.f,0.f};
    #pragma unroll
    for (int c=0; c<8; ++c){
      aH0 = mfma16(Mh[0][c], vf[c], aH0);
      aL0 = mfma16(Ml[0][c], vf[c], aL0);
    }
    const int nxt = cur ^ 1;
    { // Y finish: update, tanh, pack (v_cvt_pk_bf16_f32), LDS write
      #pragma unroll
      for (int i=0; i<4; ++i) S[1][i] += 0.01f*(aH1[i] + aL1[i]) + hb[1][i];
      float t0 = tanh_fast(S[1][0]), t1 = tanh_fast(S[1][1]);
      float t2 = tanh_fast(S[1][2]), t3 = tanh_fast(S[1][3]);
      *(uint2*)&Vb[nxt][m16][r0y] = make_uint2(pk2(t0, t1), pk2(t2, t3));
    }
    { // X finish: update, pack, LDS write
      #pragma unroll
      for (int i=0; i<4; ++i) S[0][i] += 0.01f*(aH0[i] + aL0[i]) + hb[0][i];
      *(uint2*)&Vb[nxt][m16][r0x] = make_uint2(pk2(S[0][0], S[0][1]), pk2(S[0][2], S[0][3]));
    }
    // raw barrier: drain LDS writes only; global stores stay in flight.
    asm volatile("s_waitcnt lgkmcnt(0)" ::: "memory");
    __builtin_amdgcn_s_barrier();
    asm volatile("" ::: "memory");
    cur = nxt;
    // X fp32 store after the barrier: overlaps next step's LDS reads/MFMAs.
    *(f32x4*)(op + (size_t)t*128) = S[0];
  }
}

extern "C" void kernel_launch(void* const* d_in, const int* in_sizes, int n_in,
                              void* d_out, int out_size, void* d_ws, size_t ws_size,
                              hipStream_t stream)
{
  (void)in_sizes; (void)n_in; (void)out_size; (void)ws_size;
  const float* X0  = (const float*)d_in[0];
  const float* GA1 = (const float*)d_in[1];
  const float* GAk = (const float*)d_in[2];
  const float* GAp = (const float*)d_in[3];
  const float* YA  = (const float*)d_in[4];
  const float* UA  = (const float*)d_in[5];
  const float* UB  = (const float*)d_in[6];
  const float* VB  = (const float*)d_in[7];
  const float* SBm = (const float*)d_in[8];
  const float* UC  = (const float*)d_in[9];
  const float* VC  = (const float*)d_in[10];
  const float* SCm = (const float*)d_in[11];
  const float* bx  = (const float*)d_in[12];
  const float* by  = (const float*)d_in[13];
  float* out = (float*)d_out;
  float* ws  = (float*)d_ws;

  // flag lives in out[0] (overwritten later by k_main's t=0 store)
  hipMemsetAsync(d_out, 0, 4, stream);
  k_expm<<<dim3(5),  dim3(1024), 0, stream>>>(UA, UB, VB, UC, VC, ws,
                                              SBm, SCm, GA1, GAk, GAp, YA,
                                              X0, bx, by, (unsigned int*)d_out);
  k_main<<<dim3(32), dim3(512),  0, stream>>>(ws, out);
}

// Round 3
// 695.989 us; speedup vs baseline: 1.2107x; 1.2107x over previous
//
#include <hip/hip_runtime.h>
#include <hip/hip_bf16.h>
#include <math.h>

// LurieNet: X_{t+1} = X_t + h*(A X_t + B tanh(C X_t + by) + bx), 511 steps,
// state (128 x 512 batch), output (512, 512, 128) fp32.
// Reformulated with Y := C X + by as state:  S = [X; Y] (256 x 512),
//   V = [X_bf16; tanh(Y)],  S += h*(M V) + h*b2,  M = [[A,B],[CA,CB]].
// R3 structure: TWO launches, ONE gap (~45us/gap was the #2 cost; R2 showed
// single-block serial prep is far worse than a gap):
//   k_expm  (5 blocks): 5x expm(skew(Z)) -> ws (fp32).
//   k_fused (32 blocks x 512 thr): per-block REDUNDANT prologue computes
//     C-rows/A/B/CA/CB/Y0-cols/cbx straight into loop registers (transposes
//     via per-wave LDS scratch; A/B shared via an LDS panel; all scatter in
//     LDS, all global reads vectorized), then the 511-step loop.

typedef __attribute__((ext_vector_type(8))) short short8;
typedef __attribute__((ext_vector_type(4))) float f32x4;

// workspace layout (float units): only the 5 expm outputs now
#define OFF_UO   0            // 5 * 16384 : UA_o, UB_o, VB_o, UC_o, VC_o

__device__ __forceinline__ unsigned short f2bf(float x){
  unsigned int u = __float_as_uint(x);
  unsigned int r = u + 0x7FFFu + ((u >> 16) & 1u);   // RNE
  return (unsigned short)(r >> 16);
}
__device__ __forceinline__ float bf2f(unsigned short b){
  return __uint_as_float(((unsigned int)b) << 16);
}
__device__ __forceinline__ void split_bf(float x, unsigned short& h, unsigned short& l){
  h = f2bf(x);
  l = f2bf(x - bf2f(h));
}
// v_cvt_pk_bf16_f32 path (RNE, matches f2bf): low16 = bf(a), high16 = bf(b)
__device__ __forceinline__ unsigned int pk2(float a, float b){
  union { __hip_bfloat162 h; unsigned int u; } cv;
  cv.h = __float22bfloat162_rn(make_float2(a, b));
  return cv.u;
}
__device__ __forceinline__ void split2(float x0, float x1,
                                       unsigned int& hu, unsigned int& lu){
  hu = pk2(x0, x1);
  float r0 = x0 - __uint_as_float((hu & 0xFFFFu) << 16);
  float r1 = x1 - __uint_as_float(hu & 0xFFFF0000u);
  lu = pk2(r0, r1);
}
__device__ __forceinline__ f32x4 mfma16(short8 a, short8 b, f32x4 c){
  return __builtin_amdgcn_mfma_f32_16x16x32_bf16(a, b, c, 0, 0, 0);
}
// Branchless tanh: 1 - 2/(exp(2y)+1). v_exp + v_rcp, no divergence.
__device__ __forceinline__ float tanh_fast(float y){
  float e = __expf(2.f * y);
  return 1.f - 2.f * __builtin_amdgcn_rcpf(e + 1.f);
}

// ---------------- K1: 5 x expm(skew(Z)) via Taylor-12 Horner, hi/lo bf16 MFMA
__global__ __launch_bounds__(1024) void k_expm(
    const float* __restrict__ UA, const float* __restrict__ UB,
    const float* __restrict__ VB, const float* __restrict__ UC,
    const float* __restrict__ VC, float* __restrict__ ws)
{
  const int b = blockIdx.x;
  const float* Z = (b==0)?UA:((b==1)?UB:((b==2)?VB:((b==3)?UC:VC)));
  float* Eo = ws + OFF_UO + b*16384;

  __shared__ unsigned short Hh[2][128][136];  // H^T (n-major), bf16 hi
  __shared__ unsigned short Hl[2][128][136];  // bf16 lo

  const int tid = threadIdx.x, lane = tid & 63, w = tid >> 6;
  const int q = lane >> 4, m16 = lane & 15;
  const int rt = w >> 2, cp = w & 3;

  short8 Rh[2][4], Rl[2][4];
  #pragma unroll
  for (int rr=0; rr<2; ++rr){
    const int row = rt*32 + rr*16 + m16;
    #pragma unroll
    for (int c=0; c<4; ++c){
      short8 hh, ll;
      #pragma unroll
      for (int j=0; j<8; ++j){
        const int k = c*32 + q*8 + j;
        float z = 0.f;
        if (row < k)      z =  Z[row*128 + k];
        else if (row > k) z = -Z[k*128 + row];
        unsigned short hb_, lb_;
        split_bf(z, hb_, lb_);
        hh[j] = (short)hb_; ll[j] = (short)lb_;
      }
      Rh[rr][c] = hh; Rl[rr][c] = ll;
    }
  }
  { // H = I into buffer 0
    unsigned short* hp = &Hh[0][0][0];
    unsigned short* lp = &Hl[0][0][0];
    for (int idx = tid; idx < 128*136; idx += 1024){
      const int n = idx / 136, k = idx - n*136;
      hp[idx] = (n == k) ? (unsigned short)0x3F80u : (unsigned short)0u;
      lp[idx] = 0u;
    }
  }
  __syncthreads();

  int cur = 0;
  for (int j = 12; j >= 1; --j){          // H = I + (R*H)/j
    const float rj = 1.f / (float)j;
    f32x4 acc[2][2];
    #pragma unroll
    for (int rr=0; rr<2; ++rr)
      #pragma unroll
      for (int cc=0; cc<2; ++cc) acc[rr][cc] = (f32x4){0.f,0.f,0.f,0.f};

    #pragma unroll
    for (int cc=0; cc<2; ++cc){
      const int n = cp*32 + cc*16 + m16;
      #pragma unroll
      for (int c=0; c<4; ++c){
        const short8 bh = *(const short8*)&Hh[cur][n][c*32 + q*8];
        const short8 bl = *(const short8*)&Hl[cur][n][c*32 + q*8];
        #pragma unroll
        for (int rr=0; rr<2; ++rr){
          acc[rr][cc] = mfma16(Rh[rr][c], bh, acc[rr][cc]);
          acc[rr][cc] = mfma16(Rl[rr][c], bh, acc[rr][cc]);
          acc[rr][cc] = mfma16(Rh[rr][c], bl, acc[rr][cc]);
        }
      }
    }
    if (j > 1){
      const int nxt = cur ^ 1;
      #pragma unroll
      for (int rr=0; rr<2; ++rr){
        #pragma unroll
        for (int cc=0; cc<2; ++cc){
          const int cg  = cp*32 + cc*16 + m16;
          const int rg0 = rt*32 + rr*16 + q*4;
          float x0 = acc[rr][cc][0]*rj + ((rg0+0)==cg ? 1.f : 0.f);
          float x1 = acc[rr][cc][1]*rj + ((rg0+1)==cg ? 1.f : 0.f);
          float x2 = acc[rr][cc][2]*rj + ((rg0+2)==cg ? 1.f : 0.f);
          float x3 = acc[rr][cc][3]*rj + ((rg0+3)==cg ? 1.f : 0.f);
          unsigned int h0,l0,h1,l1;
          split2(x0, x1, h0, l0);
          split2(x2, x3, h1, l1);
          *(uint2*)&Hh[nxt][cg][rg0] = make_uint2(h0, h1);
          *(uint2*)&Hl[nxt][cg][rg0] = make_uint2(l0, l1);
        }
      }
      __syncthreads();
      cur = nxt;
    } else {
      #pragma unroll
      for (int rr=0; rr<2; ++rr){
        #pragma unroll
        for (int cc=0; cc<2; ++cc){
          const int cg  = cp*32 + cc*16 + m16;
          const int rg0 = rt*32 + rr*16 + q*4;
          #pragma unroll
          for (int i=0; i<4; ++i)
            Eo[(rg0+i)*128 + cg] = acc[rr][cc][i] + ((rg0+i)==cg ? 1.f : 0.f);
        }
      }
    }
  }
}

// ---------------- k_fused helpers (512 thr = 8 waves; wave w owns M rows
// tile w (X: A|B) and tile 8+w (Y: CA|CB)).

// A-operand frags of rows [row]: lane holds U[row][c*32+q*8+j], hi/lo
__device__ __forceinline__ void load_rowfrags(const float* __restrict__ U,
    int row, int q, short8* Fh, short8* Fl)
{
  #pragma unroll
  for (int c=0; c<4; ++c){
    const float* up = U + row*128 + c*32 + q*8;
    const f32x4 u0 = *(const f32x4*)up;
    const f32x4 u1 = *(const f32x4*)(up + 4);
    short8 hh, ll;
    #pragma unroll
    for (int jj=0; jj<4; ++jj){
      unsigned short h,l;
      split_bf(u0[jj], h, l); hh[jj]   = (short)h; ll[jj]   = (short)l;
      split_bf(u1[jj], h, l); hh[jj+4] = (short)h; ll[jj+4] = (short)l;
    }
    Fh[c] = hh; Fl[c] = ll;
  }
}

// acc[ct] += (Uh/Ul rows) x (d[k]*V[n][k])^T, hi/lo 3-product; V global fp32
__device__ __forceinline__ void mm_scaledT_global(const short8* Uh, const short8* Ul,
    const float* __restrict__ V, const float* __restrict__ d,
    int q, int m16, f32x4* acc)
{
  #pragma unroll
  for (int ct=0; ct<8; ++ct){
    const int n = ct*16 + m16;
    #pragma unroll
    for (int c=0; c<4; ++c){
      const int k0 = c*32 + q*8;
      const float* vp = V + n*128 + k0;
      const f32x4 v0 = *(const f32x4*)vp;
      const f32x4 v1 = *(const f32x4*)(vp + 4);
      short8 bh, bl;
      #pragma unroll
      for (int jj=0; jj<4; ++jj){
        unsigned short h,l;
        split_bf(v0[jj]*d[k0+jj],   h, l); bh[jj]   = (short)h; bl[jj]   = (short)l;
        split_bf(v1[jj]*d[k0+4+jj], h, l); bh[jj+4] = (short)h; bl[jj+4] = (short)l;
      }
      acc[ct] = mfma16(Uh[c], bh, acc[ct]);
      acc[ct] = mfma16(Ul[c], bh, acc[ct]);
      acc[ct] = mfma16(Uh[c], bl, acc[ct]);
    }
  }
}

// acc[ct] += (Uh/Ul rows) x M_lds, B-op read strided from hi/lo LDS panel
__device__ __forceinline__ void mm_lds(const short8* Uh, const short8* Ul,
    const unsigned short (*Lh)[136], const unsigned short (*Ll)[136],
    int q, int m16, f32x4* acc)
{
  #pragma unroll
  for (int ct=0; ct<8; ++ct){
    const int n = ct*16 + m16;
    #pragma unroll
    for (int c=0; c<4; ++c){
      const int k0 = c*32 + q*8;
      short8 bh, bl;
      #pragma unroll
      for (int j=0; j<8; ++j){
        bh[j] = (short)Lh[k0+j][n];
        bl[j] = (short)Ll[k0+j][n];
      }
      acc[ct] = mfma16(Uh[c], bh, acc[ct]);
      acc[ct] = mfma16(Ul[c], bh, acc[ct]);
      acc[ct] = mfma16(Uh[c], bl, acc[ct]);
    }
  }
}

// C/D-layout acc (lane holds [q*4+i][ct*16+m16]) -> hi/lo LDS rows rowbase..
__device__ __forceinline__ void acc_to_lds(const f32x4* acc, int rowbase,
    int q, int m16, unsigned short (*Lh)[136], unsigned short (*Ll)[136])
{
  #pragma unroll
  for (int ct=0; ct<8; ++ct){
    #pragma unroll
    for (int i=0; i<4; ++i){
      unsigned short h,l; split_bf(acc[ct][i], h, l);
      Lh[rowbase + q*4 + i][ct*16 + m16] = h;
      Ll[rowbase + q*4 + i][ct*16 + m16] = l;
    }
  }
}

// read A-op frags (4 chunks) for row `row` from hi/lo LDS panel
__device__ __forceinline__ void frags_from(const unsigned short (*Lh)[136],
    const unsigned short (*Ll)[136], int row, int q, short8* Fh, short8* Fl)
{
  #pragma unroll
  for (int c=0; c<4; ++c){
    Fh[c] = *(const short8*)&Lh[row][c*32 + q*8];
    Fl[c] = *(const short8*)&Ll[row][c*32 + q*8];
  }
}

// ---------------- K2: redundant prologue + 511-step recurrence.
__global__ __launch_bounds__(512) void k_fused(
    const float* __restrict__ ws, const float* __restrict__ X0,
    const float* __restrict__ SBm, const float* __restrict__ SCm,
    const float* __restrict__ GA1, const float* __restrict__ GAk,
    const float* __restrict__ GAp, const float* __restrict__ YA,
    const float* __restrict__ bx, const float* __restrict__ by,
    float* __restrict__ out)
{
  __shared__ unsigned short Lds[2][128][136];   // shared hi/lo matrix (A, then B)
  __shared__ unsigned short Scr[8][2][16][136]; // per-wave transpose scratch
  __shared__ unsigned short Vb[2][16][264];     // V^T double buffer (loop)
  __shared__ float sbv[128], scv[128], bxs[128], bys[128], dvec[128];
  __shared__ float scal[4];

  const int tid = threadIdx.x, lane = tid & 63, w = tid >> 6, wg = blockIdx.x;
  const int q = lane >> 4, m16 = lane & 15;

  const float* UAo = ws + OFF_UO;
  const float* UBo = ws + OFF_UO + 16384;
  const float* VBo = ws + OFF_UO + 32768;
  const float* UCo = ws + OFF_UO + 49152;
  const float* VCo = ws + OFF_UO + 65536;

  unsigned short (*ScrH)[136] = (unsigned short (*)[136])&Scr[w][0][0][0];
  unsigned short (*ScrL)[136] = (unsigned short (*)[136])&Scr[w][1][0][0];
  unsigned short (*LdsH)[136] = (unsigned short (*)[136])&Lds[0][0][0];
  unsigned short (*LdsL)[136] = (unsigned short (*)[136])&Lds[1][0][0];

  short8 Mh[2][8], Ml[2][8];
  short8 Ch[4], Cl[4];
  f32x4 S[2], hb[2];

  // ---- P0: stage diagonals/vectors; SA scalars
  if (tid < 128){
    sbv[tid] = fabsf(SBm[tid*129]);
    scv[tid] = fabsf(SCm[tid*129]);
    bxs[tid] = bx[tid];
    bys[tid] = by[tid];
  }
  __syncthreads();
  if (tid == 0){
    float b1=0.f,b2=0.f,c1=0.f,c2=0.f;
    for (int i=0;i<128;++i){
      float vb = sbv[i];
      if (vb > b1){ b2=b1; b1=vb; } else if (vb > b2) b2=vb;
      float vc = scv[i];
      if (vc > c1){ c2=c1; c1=vc; } else if (vc > c2) c2=vc;
    }
    float alpha = sqrtf(8.f*(b1*b1*c1*c1 + b2*b2*c2*c2));  // 4*K*G^2 = 8
    float sa0 = GA1[0];
    float sa2 = -(alpha + sa0) - (fabsf(GAk[0]) + 1e-5f);
    scal[0]=sa0; scal[1]=sa2; scal[2]=fminf(fminf(sa0, sa2), 0.f);
  }
  __syncthreads();
  if (tid < 128){
    dvec[tid] = (tid==0) ? scal[0]
              : (tid==1) ? scal[1]
              : scal[2] - fabsf(GAp[(tid-2)*127]);
  }
  __syncthreads();

  // ---- P1: C rows [16w,16w+16); cbx (-> hb[1]); Y0 cols (-> S[1])
  {
    short8 Uh[4], Ul[4];
    load_rowfrags(UCo, w*16 + m16, q, Uh, Ul);
    f32x4 acc[8];
    #pragma unroll
    for (int ct=0; ct<8; ++ct) acc[ct] = (f32x4){0.f,0.f,0.f,0.f};
    mm_scaledT_global(Uh, Ul, VCo, scv, q, m16, acc);

    // cbx = C @ bx: partial over this lane's cols, reduce over m16 group
    float cb0=0.f, cb1=0.f, cb2=0.f, cb3=0.f;
    #pragma unroll
    for (int ct=0; ct<8; ++ct){
      const float bxv = bxs[ct*16 + m16];
      cb0 += acc[ct][0]*bxv; cb1 += acc[ct][1]*bxv;
      cb2 += acc[ct][2]*bxv; cb3 += acc[ct][3]*bxv;
    }
    #pragma unroll
    for (int m=1; m<16; m<<=1){
      cb0 += __shfl_xor(cb0, m); cb1 += __shfl_xor(cb1, m);
      cb2 += __shfl_xor(cb2, m); cb3 += __shfl_xor(cb3, m);
    }
    hb[1] = (f32x4){0.01f*cb0, 0.01f*cb1, 0.01f*cb2, 0.01f*cb3};

    // C rows -> per-wave scratch -> A-op frags (Ch/Cl)
    acc_to_lds(acc, 0, q, m16, ScrH, ScrL);
    __syncthreads();
    frags_from(ScrH, ScrL, m16, q, Ch, Cl);

    // Y0 rows [16w..) for this block's 16 batch cols: S[1] = C.X0cols + by
    f32x4 accY = (f32x4){0.f,0.f,0.f,0.f};
    const float* xp = X0 + (size_t)(wg*16 + m16)*128;
    #pragma unroll
    for (int c=0; c<4; ++c){
      const int k0 = c*32 + q*8;
      const f32x4 x0v = *(const f32x4*)(xp + k0);
      const f32x4 x1v = *(const f32x4*)(xp + k0 + 4);
      short8 bh, bl;
      #pragma unroll
      for (int jj=0; jj<4; ++jj){
        unsigned short h,l;
        split_bf(x0v[jj], h, l); bh[jj]   = (short)h; bl[jj]   = (short)l;
        split_bf(x1v[jj], h, l); bh[jj+4] = (short)h; bl[jj+4] = (short)l;
      }
      accY = mfma16(Ch[c], bh, accY);
      accY = mfma16(Cl[c], bh, accY);
      accY = mfma16(Ch[c], bl, accY);
    }
    #pragma unroll
    for (int i=0; i<4; ++i) S[1][i] = accY[i] + bys[w*16 + q*4 + i];
  }

  // ---- P2: A = 0.5*U.diag(dvec).U^T + 0.5*skew(YA); share via LDS panel
  {
    short8 Uh[4], Ul[4];
    load_rowfrags(UAo, w*16 + m16, q, Uh, Ul);
    f32x4 acc[8];
    #pragma unroll
    for (int ct=0; ct<8; ++ct) acc[ct] = (f32x4){0.f,0.f,0.f,0.f};
    mm_scaledT_global(Uh, Ul, UAo, dvec, q, m16, acc);
    #pragma unroll
    for (int ct=0; ct<8; ++ct){
      const int cg = ct*16 + m16;
      #pragma unroll
      for (int i=0; i<4; ++i){
        const int r = w*16 + q*4 + i;
        float sk = 0.f;
        if (r < cg) sk = YA[r*128 + cg];
        else if (r > cg) sk = -YA[cg*128 + r];
        acc[ct][i] = 0.5f*acc[ct][i] + 0.5f*sk;
      }
    }
    acc_to_lds(acc, w*16, q, m16, LdsH, LdsL);
  }
  __syncthreads();
  // M X-frags (A half) + CA rows -> M Y-frags (k<128 half)
  frags_from(LdsH, LdsL, w*16 + m16, q, &Mh[0][0], &Ml[0][0]);
  {
    f32x4 acc[8];
    #pragma unroll
    for (int ct=0; ct<8; ++ct) acc[ct] = (f32x4){0.f,0.f,0.f,0.f};
    mm_lds(Ch, Cl, LdsH, LdsL, q, m16, acc);
    acc_to_lds(acc, 0, q, m16, ScrH, ScrL);
    __syncthreads();
    frags_from(ScrH, ScrL, m16, q, &Mh[1][0], &Ml[1][0]);
  }
  __syncthreads();   // all LDS-panel reads done before B overwrites

  // ---- P3: B = U.diag(sb).V^T; M X-frags (B half); CB -> M Y-frags
  {
    short8 Uh[4], Ul[4];
    load_rowfrags(UBo, w*16 + m16, q, Uh, Ul);
    f32x4 acc[8];
    #pragma unroll
    for (int ct=0; ct<8; ++ct) acc[ct] = (f32x4){0.f,0.f,0.f,0.f};
    mm_scaledT_global(Uh, Ul, VBo, sbv, q, m16, acc);
    acc_to_lds(acc, w*16, q, m16, LdsH, LdsL);
  }
  __syncthreads();
  frags_from(LdsH, LdsL, w*16 + m16, q, &Mh[0][4], &Ml[0][4]);
  {
    f32x4 acc[8];
    #pragma unroll
    for (int ct=0; ct<8; ++ct) acc[ct] = (f32x4){0.f,0.f,0.f,0.f};
    mm_lds(Ch, Cl, LdsH, LdsL, q, m16, acc);
    acc_to_lds(acc, 0, q, m16, ScrH, ScrL);
    __syncthreads();
    frags_from(ScrH, ScrL, m16, q, &Mh[1][4], &Ml[1][4]);
  }
  __syncthreads();

  // ---- P4: loop state init + t=0 output + V init
  const int r0x = w*16 + q*4;           // owned X rows (V position = row)
  const int r0y = 128 + w*16 + q*4;     // owned Y rows (V position = 128+row)

  S[0] = *(const f32x4*)(X0 + (size_t)(wg*16 + m16)*128 + r0x);
  hb[0] = (f32x4){0.01f*bxs[r0x], 0.01f*bxs[r0x+1],
                  0.01f*bxs[r0x+2], 0.01f*bxs[r0x+3]};

  float* op = out + (size_t)(wg*16 + m16)*65536 + r0x;   // + t*128
  *(f32x4*)op = S[0];                   // t = 0 output

  { // initial V = [X0_bf16 ; tanh(Y0)]
    *(uint2*)&Vb[0][m16][r0x] = make_uint2(pk2(S[0][0], S[0][1]), pk2(S[0][2], S[0][3]));
    float t0 = tanh_fast(S[1][0]), t1 = tanh_fast(S[1][1]);
    float t2 = tanh_fast(S[1][2]), t3 = tanh_fast(S[1][3]);
    *(uint2*)&Vb[0][m16][r0y] = make_uint2(pk2(t0, t1), pk2(t2, t3));
  }
  asm volatile("s_waitcnt lgkmcnt(0)" ::: "memory");
  __builtin_amdgcn_s_barrier();
  asm volatile("" ::: "memory");

  // ---- 511-step loop (symmetric waves; Y MFMAs first; raw lgkm-only barrier)
  int cur = 0;
  for (int t = 1; t < 512; ++t){
    const unsigned short* vrow = &Vb[cur][m16][q*8];
    short8 vf[8];
    #pragma unroll
    for (int c=0; c<8; ++c) vf[c] = *(const short8*)(vrow + c*32);

    f32x4 aH1 = (f32x4){0.f,0.f,0.f,0.f}, aL1 = (f32x4){0.f,0.f,0.f,0.f};
    #pragma unroll
    for (int c=0; c<8; ++c){
      aH1 = mfma16(Mh[1][c], vf[c], aH1);
      aL1 = mfma16(Ml[1][c], vf[c], aL1);
    }
    f32x4 aH0 = (f32x4){0.f,0.f,0.f,0.f}, aL0 = (f32x4){0.f,0.f,0.f,0.f};
    #pragma unroll
    for (int c=0; c<8; ++c){
      aH0 = mfma16(Mh[0][c], vf[c], aH0);
      aL0 = mfma16(Ml[0][c], vf[c], aL0);
    }
    const int nxt = cur ^ 1;
    { // Y finish: update, tanh, pack, LDS write
      #pragma unroll
      for (int i=0; i<4; ++i) S[1][i] += 0.01f*(aH1[i] + aL1[i]) + hb[1][i];
      float t0 = tanh_fast(S[1][0]), t1 = tanh_fast(S[1][1]);
      float t2 = tanh_fast(S[1][2]), t3 = tanh_fast(S[1][3]);
      *(uint2*)&Vb[nxt][m16][r0y] = make_uint2(pk2(t0, t1), pk2(t2, t3));
    }
    { // X finish: update, pack, LDS write
      #pragma unroll
      for (int i=0; i<4; ++i) S[0][i] += 0.01f*(aH0[i] + aL0[i]) + hb[0][i];
      *(uint2*)&Vb[nxt][m16][r0x] = make_uint2(pk2(S[0][0], S[0][1]), pk2(S[0][2], S[0][3]));
    }
    asm volatile("s_waitcnt lgkmcnt(0)" ::: "memory");
    __builtin_amdgcn_s_barrier();
    asm volatile("" ::: "memory");
    cur = nxt;
    *(f32x4*)(op + (size_t)t*128) = S[0];
  }
}

extern "C" void kernel_launch(void* const* d_in, const int* in_sizes, int n_in,
                              void* d_out, int out_size, void* d_ws, size_t ws_size,
                              hipStream_t stream)
{
  (void)in_sizes; (void)n_in; (void)out_size; (void)ws_size;
  const float* X0  = (const float*)d_in[0];
  const float* GA1 = (const float*)d_in[1];
  const float* GAk = (const float*)d_in[2];
  const float* GAp = (const float*)d_in[3];
  const float* YA  = (const float*)d_in[4];
  const float* UA  = (const float*)d_in[5];
  const float* UB  = (const float*)d_in[6];
  const float* VB  = (const float*)d_in[7];
  const float* SBm = (const float*)d_in[8];
  const float* UC  = (const float*)d_in[9];
  const float* VC  = (const float*)d_in[10];
  const float* SCm = (const float*)d_in[11];
  const float* bx  = (const float*)d_in[12];
  const float* by  = (const float*)d_in[13];
  float* out = (float*)d_out;
  float* ws  = (float*)d_ws;

  k_expm <<<dim3(5),  dim3(1024), 0, stream>>>(UA, UB, VB, UC, VC, ws);
  k_fused<<<dim3(32), dim3(512),  0, stream>>>(ws, X0, SBm, SCm, GA1, GAk, GAp,
                                               YA, bx, by, out);
}